// Round 1
// baseline (703.201 us; speedup 1.0000x reference)
//
#include <hip/hip_runtime.h>
#include <math.h>

// Problem constants (fixed by the reference)
#define LEN   5440          // 64*64 + 32*32 + 16*16 + 8*8
#define NTOK  21760         // B(4) * LEN
#define CDIM  256
#define HEADS 8
#define DH    32
#define DFF   1024
#define LEPS  1e-5f

// ---------------- float4 helpers ----------------
__device__ __forceinline__ float4 f4_add(float4 a, float4 b) {
    return make_float4(a.x + b.x, a.y + b.y, a.z + b.z, a.w + b.w);
}

// ---------------- weight packing ----------------
// Wcat[k][c], k in [0,256), c in [0,640): [w_off(256) | w_attn(128) | w_val(256)]
__global__ void pack_kernel(const float* __restrict__ w_off, const float* __restrict__ w_attn,
                            const float* __restrict__ w_val, const float* __restrict__ b_off,
                            const float* __restrict__ b_attn, const float* __restrict__ b_val,
                            float* __restrict__ Wcat, float* __restrict__ bcat) {
    int i = blockIdx.x * 256 + threadIdx.x;
    if (i < 256 * 640) {
        int k = i / 640, c = i % 640;
        float v;
        if (c < 256)      v = w_off[k * 256 + c];
        else if (c < 384) v = w_attn[k * 128 + (c - 256)];
        else              v = w_val[k * 256 + (c - 384)];
        Wcat[i] = v;
    }
    if (i < 640) {
        float v;
        if (i < 256)      v = b_off[i];
        else if (i < 384) v = b_attn[i - 256];
        else              v = b_val[i - 384];
        bcat[i] = v;
    }
}

// ---------------- fp32 tiled GEMM: C[M,N] = A[M,K] @ B[K,N] + bias, opt ReLU ----
// 128x128 tile, KB=8, 256 threads, 8x8 microtile per thread.
// DUALA: for column tiles with bx*128 < colSwitch, A-tile = A + A2 (q = src+pos).
#define TS 128
#define KB 8
template <bool DUALA, bool RELU>
__global__ __launch_bounds__(256) void gemm_k(const float* __restrict__ A,
                                              const float* __restrict__ A2,
                                              const float* __restrict__ B,
                                              const float* __restrict__ bias,
                                              float* __restrict__ C,
                                              int M, int Nn, int K, int colSwitch) {
    __shared__ float As[KB][TS];
    __shared__ float Bs[KB][TS];
    const int bx = blockIdx.x, by = blockIdx.y;
    const int tid = threadIdx.x;
    const int tx = tid & 15, ty = tid >> 4;
    const bool useA2 = DUALA && (bx * TS < colSwitch);

    float acc[8][8];
#pragma unroll
    for (int i = 0; i < 8; ++i)
#pragma unroll
        for (int j = 0; j < 8; ++j) acc[i][j] = 0.f;

    const int arow = tid >> 1;          // 0..127
    const int akk  = (tid & 1) * 4;     // 0 or 4
    const int bkk  = tid >> 5;          // 0..7
    const int bcol = (tid & 31) * 4;    // 0..124

    const float* Ab  = A + (size_t)(by * TS) * K;
    const float* A2b = DUALA ? (A2 + (size_t)(by * TS) * K) : nullptr;
    const float* Bb  = B + (size_t)bx * TS;

    for (int k0 = 0; k0 < K; k0 += KB) {
        float4 av = *(const float4*)&Ab[(size_t)arow * K + k0 + akk];
        if (DUALA && useA2) {
            float4 a2 = *(const float4*)&A2b[(size_t)arow * K + k0 + akk];
            av = f4_add(av, a2);
        }
        As[akk + 0][arow] = av.x;
        As[akk + 1][arow] = av.y;
        As[akk + 2][arow] = av.z;
        As[akk + 3][arow] = av.w;
        float4 bv = *(const float4*)&Bb[(size_t)(k0 + bkk) * Nn + bcol];
        *(float4*)&Bs[bkk][bcol] = bv;
        __syncthreads();
#pragma unroll
        for (int kk = 0; kk < KB; ++kk) {
            float a[8], b[8];
            float4 t0 = *(const float4*)&As[kk][ty * 8];
            float4 t1 = *(const float4*)&As[kk][ty * 8 + 4];
            a[0] = t0.x; a[1] = t0.y; a[2] = t0.z; a[3] = t0.w;
            a[4] = t1.x; a[5] = t1.y; a[6] = t1.z; a[7] = t1.w;
            float4 u0 = *(const float4*)&Bs[kk][tx * 8];
            float4 u1 = *(const float4*)&Bs[kk][tx * 8 + 4];
            b[0] = u0.x; b[1] = u0.y; b[2] = u0.z; b[3] = u0.w;
            b[4] = u1.x; b[5] = u1.y; b[6] = u1.z; b[7] = u1.w;
#pragma unroll
            for (int i = 0; i < 8; ++i)
#pragma unroll
                for (int j = 0; j < 8; ++j) acc[i][j] = fmaf(a[i], b[j], acc[i][j]);
        }
        __syncthreads();
    }

    const int crow = by * TS + ty * 8;
    const int ccol = bx * TS + tx * 8;
    float bj[8];
#pragma unroll
    for (int j = 0; j < 8; ++j) bj[j] = bias[ccol + j];
#pragma unroll
    for (int i = 0; i < 8; ++i) {
        float o[8];
#pragma unroll
        for (int j = 0; j < 8; ++j) {
            float v = acc[i][j] + bj[j];
            if (RELU) v = fmaxf(v, 0.f);
            o[j] = v;
        }
        *(float4*)&C[(size_t)(crow + i) * Nn + ccol]     = make_float4(o[0], o[1], o[2], o[3]);
        *(float4*)&C[(size_t)(crow + i) * Nn + ccol + 4] = make_float4(o[4], o[5], o[6], o[7]);
    }
}

// ---------------- MSDA: fused softmax + bilinear gather ----------------
// C1 row layout per token n: [0,256) = offsets, [256,384) = attn logits, [384,640) = value.
// Block = 256 threads = 4 tokens * 8 heads * 8 channel-quads.
__global__ __launch_bounds__(256) void msda_kernel(const float* __restrict__ C1,
                                                   const float* __restrict__ refp,
                                                   float* __restrict__ out) {
    const int tid  = threadIdx.x;
    const int g    = tid & 7;          // channel quad
    const int pair = tid >> 3;         // 0..31
    const int h    = pair & 7;
    const int n    = blockIdx.x * 4 + (pair >> 3);
    const int b    = n / LEN;
    const size_t rowb = (size_t)n * 640;

    // softmax over 16 (l,p) logits for this head (redundant across the 8 lanes of the group)
    float lg[16];
    float mx = -1e30f;
#pragma unroll
    for (int s = 0; s < 16; ++s) {
        lg[s] = C1[rowb + 256 + h * 16 + s];
        mx = fmaxf(mx, lg[s]);
    }
    float sum = 0.f;
#pragma unroll
    for (int s = 0; s < 16; ++s) {
        lg[s] = expf(lg[s] - mx);
        sum += lg[s];
    }
    const float inv = 1.f / sum;

    const int Wi[4] = {64, 32, 16, 8};
    const int st[4] = {0, 4096, 5120, 5376};
    float4 acc = make_float4(0.f, 0.f, 0.f, 0.f);
    const int vbase_h = 384 + h * 32 + g * 4;

#pragma unroll
    for (int l = 0; l < 4; ++l) {
        const int   W  = Wi[l];
        const float Wf = (float)W;      // levels are square: Hl == Wl
        const float rx = refp[((size_t)n * 4 + l) * 2 + 0];
        const float ry = refp[((size_t)n * 4 + l) * 2 + 1];
#pragma unroll
        for (int p = 0; p < 4; ++p) {
            const float aw = lg[l * 4 + p] * inv;
            const float ox = C1[rowb + (size_t)(((h * 4 + l) * 4 + p) * 2 + 0)];
            const float oy = C1[rowb + (size_t)(((h * 4 + l) * 4 + p) * 2 + 1)];
            // match reference op order: loc = ref + off/W ; p = loc*W - 0.5
            const float lx = rx + ox / Wf;
            const float ly = ry + oy / Wf;
            const float px = lx * Wf - 0.5f;
            const float py = ly * Wf - 0.5f;
            const float x0f = floorf(px), y0f = floorf(py);
            const float wx1 = px - x0f, wy1 = py - y0f;
            const int x0 = (int)x0f, y0 = (int)y0f;
#pragma unroll
            for (int c = 0; c < 4; ++c) {
                const int dx = c & 1, dy = c >> 1;
                const int ix = x0 + dx, iy = y0 + dy;
                const float wgt = (dx ? wx1 : 1.f - wx1) * (dy ? wy1 : 1.f - wy1);
                const bool valid = (ix >= 0) && (ix < W) && (iy >= 0) && (iy < W);
                const int ixc = min(max(ix, 0), W - 1);
                const int iyc = min(max(iy, 0), W - 1);
                const int pos = st[l] + iyc * W + ixc;
                const float4 v = *(const float4*)&C1[((size_t)(b * LEN + pos)) * 640 + vbase_h];
                const float wa = valid ? (aw * wgt) : 0.f;
                acc.x = fmaf(wa, v.x, acc.x);
                acc.y = fmaf(wa, v.y, acc.y);
                acc.z = fmaf(wa, v.z, acc.z);
                acc.w = fmaf(wa, v.w, acc.w);
            }
        }
    }
    *(float4*)&out[(size_t)n * 256 + h * 32 + g * 4] = acc;
}

// ---------------- LayerNorm (wave per token): O = LN(Y + R) * g + b ----------------
__global__ __launch_bounds__(256) void ln_kernel(const float* __restrict__ Y,
                                                 const float* __restrict__ R,
                                                 const float* __restrict__ gm,
                                                 const float* __restrict__ bt,
                                                 float* __restrict__ O) {
    const int wave = threadIdx.x >> 6, lane = threadIdx.x & 63;
    const int n = blockIdx.x * 4 + wave;
    const size_t base = (size_t)n * 256 + lane * 4;
    float4 y = *(const float4*)&Y[base];
    float4 r = *(const float4*)&R[base];
    float4 v = f4_add(y, r);
    float s = v.x + v.y + v.z + v.w;
#pragma unroll
    for (int m = 1; m < 64; m <<= 1) s += __shfl_xor(s, m, 64);
    const float mean = s * (1.f / 256.f);
    const float dx = v.x - mean, dy = v.y - mean, dz = v.z - mean, dw = v.w - mean;
    float ss = dx * dx + dy * dy + dz * dz + dw * dw;
#pragma unroll
    for (int m = 1; m < 64; m <<= 1) ss += __shfl_xor(ss, m, 64);
    const float rstd = rsqrtf(ss * (1.f / 256.f) + LEPS);
    const float4 g4 = *(const float4*)&gm[lane * 4];
    const float4 b4 = *(const float4*)&bt[lane * 4];
    float4 o;
    o.x = dx * rstd * g4.x + b4.x;
    o.y = dy * rstd * g4.y + b4.y;
    o.z = dz * rstd * g4.z + b4.z;
    o.w = dw * rstd * g4.w + b4.w;
    *(float4*)&O[base] = o;
}

// ---------------- launch ----------------
extern "C" void kernel_launch(void* const* d_in, const int* in_sizes, int n_in,
                              void* d_out, int out_size, void* d_ws, size_t ws_size,
                              hipStream_t stream) {
    const float* src   = (const float*)d_in[0];
    const float* pos   = (const float*)d_in[1];
    const float* refp  = (const float*)d_in[2];
    // d_in[3] spatial_shapes, d_in[4] level_start_index, d_in[5] valid_ratios: hardcoded
    const float* w_off  = (const float*)d_in[6];
    const float* b_off  = (const float*)d_in[7];
    const float* w_attn = (const float*)d_in[8];
    const float* b_attn = (const float*)d_in[9];
    const float* w_val  = (const float*)d_in[10];
    const float* b_val  = (const float*)d_in[11];
    const float* w_out  = (const float*)d_in[12];
    const float* b_out  = (const float*)d_in[13];
    const float* g1     = (const float*)d_in[14];
    const float* be1    = (const float*)d_in[15];
    const float* w1     = (const float*)d_in[16];
    const float* b1     = (const float*)d_in[17];
    const float* w2     = (const float*)d_in[18];
    const float* b2     = (const float*)d_in[19];
    const float* g2     = (const float*)d_in[20];
    const float* be2    = (const float*)d_in[21];

    float* ws = (float*)d_ws;
    // workspace layout (floats); total 47,514,240 floats ~= 181.3 MB
    float* C1   = ws + 0;            // [N,640]  off|attn|value
    float* msda = ws + 13926400;     // [N,256]
    float* xbuf = ws + 19496960;     // [N,256]
    float* hbuf = ws + 25067520;     // [N,1024]
    float* Wcat = ws + 47349760;     // [256,640]
    float* bcat = ws + 47513600;     // [640]
    float* ybuf = C1;                // alias: C1 dead after msda

    pack_kernel<<<640, 256, 0, stream>>>(w_off, w_attn, w_val, b_off, b_attn, b_val, Wcat, bcat);

    // [N,640] = (src+pos | src) @ Wcat + bcat   (cols < 384 use q = src+pos)
    gemm_k<true, false><<<dim3(5, 170), 256, 0, stream>>>(src, pos, Wcat, bcat, C1,
                                                          NTOK, 640, 256, 384);

    msda_kernel<<<NTOK / 4, 256, 0, stream>>>(C1, refp, msda);

    // y = msda @ w_out + b_out
    gemm_k<false, false><<<dim3(2, 170), 256, 0, stream>>>(msda, nullptr, w_out, b_out, ybuf,
                                                           NTOK, 256, 256, 0);
    // x = LN(y + src)
    ln_kernel<<<NTOK / 4, 256, 0, stream>>>(ybuf, src, g1, be1, xbuf);

    // h = relu(x @ w1 + b1)
    gemm_k<false, true><<<dim3(8, 170), 256, 0, stream>>>(xbuf, nullptr, w1, b1, hbuf,
                                                          NTOK, DFF, 256, 0);
    // y2 = h @ w2 + b2
    gemm_k<false, false><<<dim3(2, 170), 256, 0, stream>>>(hbuf, nullptr, w2, b2, ybuf,
                                                           NTOK, 256, DFF, 0);
    // out = LN(y2 + x)
    ln_kernel<<<NTOK / 4, 256, 0, stream>>>(ybuf, xbuf, g2, be2, (float*)d_out);
}

// Round 2
// 323.687 us; speedup vs baseline: 2.1725x; 2.1725x over previous
//
#include <hip/hip_runtime.h>
#include <hip/hip_fp16.h>
#include <math.h>

// Problem constants (fixed by the reference)
#define LEN   5440          // 64*64 + 32*32 + 16*16 + 8*8
#define NTOK  21760         // B(4) * LEN
#define CDIM  256
#define HEADS 8
#define DFF   1024
#define LEPS  1e-5f

typedef __attribute__((ext_vector_type(8))) _Float16 f16x8;
typedef __attribute__((ext_vector_type(4))) float f32x4;

__device__ __forceinline__ float4 f4_add(float4 a, float4 b) {
    return make_float4(a.x + b.x, a.y + b.y, a.z + b.z, a.w + b.w);
}

// ---------------- pack: weights -> fp16, transposed to [N][K] ----------------
// WcatT [640][256] = [w_off | w_attn | w_val]^T ; woutT [256][256]; w1T [1024][256];
// w2T [256][1024]; bcat [640] fp32.
__global__ __launch_bounds__(256) void pack_k(const float* __restrict__ w_off,
                                              const float* __restrict__ w_attn,
                                              const float* __restrict__ w_val,
                                              const float* __restrict__ b_off,
                                              const float* __restrict__ b_attn,
                                              const float* __restrict__ b_val,
                                              const float* __restrict__ w_out,
                                              const float* __restrict__ w1,
                                              const float* __restrict__ w2,
                                              __half* __restrict__ WcatT,
                                              __half* __restrict__ woutT,
                                              __half* __restrict__ w1T,
                                              __half* __restrict__ w2T,
                                              float* __restrict__ bcat) {
    const int i = blockIdx.x * 256 + threadIdx.x;
    if (i < 163840) {                      // WcatT [c<640][k<256]
        const int c = i >> 8, k = i & 255;
        float v;
        if (c < 256)      v = w_off[k * 256 + c];
        else if (c < 384) v = w_attn[k * 128 + (c - 256)];
        else              v = w_val[k * 256 + (c - 384)];
        WcatT[i] = __float2half(v);
    } else if (i < 229376) {               // woutT [c<256][k<256]
        const int j = i - 163840, c = j >> 8, k = j & 255;
        woutT[j] = __float2half(w_out[k * 256 + c]);
    } else if (i < 491520) {               // w1T [c<1024][k<256]
        const int j = i - 229376, c = j >> 8, k = j & 255;
        w1T[j] = __float2half(w1[k * 1024 + c]);
    } else if (i < 753664) {               // w2T [c<256][k<1024]
        const int j = i - 491520, c = j >> 10, k = j & 1023;
        w2T[j] = __float2half(w2[k * 256 + c]);
    }
    if (i < 640) {
        bcat[i] = (i < 256) ? b_off[i] : (i < 384) ? b_attn[i - 256] : b_val[i - 384];
    }
}

// ---------------- cvt: qh = half(src+pos), srch = half(src) ----------------
__global__ __launch_bounds__(256) void cvt_k(const float* __restrict__ src,
                                             const float* __restrict__ pos,
                                             __half* __restrict__ qh,
                                             __half* __restrict__ srch) {
    const size_t i = (size_t)blockIdx.x * 256 + threadIdx.x;   // 4 elems each
    float4 s = *(const float4*)&src[i * 4];
    float4 p = *(const float4*)&pos[i * 4];
    union { __half2 h[2]; uint2 u; } Q, S;
    Q.h[0] = __floats2half2_rn(s.x + p.x, s.y + p.y);
    Q.h[1] = __floats2half2_rn(s.z + p.z, s.w + p.w);
    S.h[0] = __floats2half2_rn(s.x, s.y);
    S.h[1] = __floats2half2_rn(s.z, s.w);
    *(uint2*)&qh[i * 4]   = Q.u;
    *(uint2*)&srch[i * 4] = S.u;
}

// ---------------- fp16 MFMA GEMM: C[M,N] = A[M,K] @ Bt[N,K]^T + bias ----------------
// 128x128 tile, BK=32, 4 waves, each wave 64x64 via 4x4 frags of 16x16x32 MFMA.
// A-select: column tiles with bx*128 < colSwitch use Aq, else Av.
template <bool RELU, bool OUTF, bool OUTH>
__global__ __launch_bounds__(256) void hgemm_k(const __half* __restrict__ Aq,
                                               const __half* __restrict__ Av,
                                               const __half* __restrict__ Bt,
                                               const float* __restrict__ bias,
                                               float* __restrict__ Cf,
                                               __half* __restrict__ Ch,
                                               int Nn, int K, int colSwitch) {
    __shared__ __half As[128][40];   // padded stride 40 halfs = 80 B
    __shared__ __half Bs[128][40];
    const int bx = blockIdx.x, by = blockIdx.y;
    const int tid = threadIdx.x;
    const int lane = tid & 63;
    const int wave = tid >> 6;
    const int wr = (wave >> 1) * 64;
    const int wc = (wave & 1) * 64;

    const __half* __restrict__ Ah = (bx * 128 < colSwitch) ? Aq : Av;
    const __half* Abase = Ah + (size_t)(by * 128) * K;
    const __half* Bbase = Bt + (size_t)(bx * 128) * K;

    // staging: thread t owns row t>>1, 16 contiguous halfs at k-offset (t&1)*16
    const int srow = tid >> 1;
    const int sk = (tid & 1) * 16;

    f32x4 acc[4][4];
#pragma unroll
    for (int m = 0; m < 4; ++m)
#pragma unroll
        for (int n = 0; n < 4; ++n) acc[m][n] = (f32x4){0.f, 0.f, 0.f, 0.f};

    const int fr = lane & 15;
    const int fk = (lane >> 4) * 8;

    for (int k0 = 0; k0 < K; k0 += 32) {
        const uint4 a0 = *(const uint4*)&Abase[(size_t)srow * K + k0 + sk];
        const uint4 a1 = *(const uint4*)&Abase[(size_t)srow * K + k0 + sk + 8];
        const uint4 b0 = *(const uint4*)&Bbase[(size_t)srow * K + k0 + sk];
        const uint4 b1 = *(const uint4*)&Bbase[(size_t)srow * K + k0 + sk + 8];
        __syncthreads();   // previous iteration's reads done before overwrite
        *(uint4*)&As[srow][sk]     = a0;
        *(uint4*)&As[srow][sk + 8] = a1;
        *(uint4*)&Bs[srow][sk]     = b0;
        *(uint4*)&Bs[srow][sk + 8] = b1;
        __syncthreads();
        f16x8 af[4], bf[4];
#pragma unroll
        for (int m = 0; m < 4; ++m) af[m] = *(const f16x8*)&As[wr + m * 16 + fr][fk];
#pragma unroll
        for (int n = 0; n < 4; ++n) bf[n] = *(const f16x8*)&Bs[wc + n * 16 + fr][fk];
#pragma unroll
        for (int m = 0; m < 4; ++m)
#pragma unroll
            for (int n = 0; n < 4; ++n)
                acc[m][n] = __builtin_amdgcn_mfma_f32_16x16x32_f16(af[m], bf[n], acc[m][n], 0, 0, 0);
    }

    // C/D layout (m89): col = lane&15, row = (lane>>4)*4 + reg
    const int rowb = by * 128 + wr + (lane >> 4) * 4;
    const int colb = bx * 128 + wc + fr;
    float bn[4];
#pragma unroll
    for (int n = 0; n < 4; ++n) bn[n] = bias[colb + n * 16];
#pragma unroll
    for (int m = 0; m < 4; ++m) {
#pragma unroll
        for (int r = 0; r < 4; ++r) {
            const size_t ro = (size_t)(rowb + m * 16 + r) * Nn + colb;
#pragma unroll
            for (int n = 0; n < 4; ++n) {
                float v = acc[m][n][r] + bn[n];
                if (RELU) v = fmaxf(v, 0.f);
                if (OUTF) Cf[ro + n * 16] = v;
                if (OUTH) Ch[ro + n * 16] = __float2half(v);
            }
        }
    }
}

// ---------------- MSDA: fused softmax + bilinear gather (fp16 output) ----------------
// C1 row layout per token n: [0,256) = offsets, [256,384) = attn logits, [384,640) = value.
// Block = 256 threads = 4 tokens * 8 heads * 8 channel-quads.
__global__ __launch_bounds__(256) void msda_kernel(const float* __restrict__ C1,
                                                   const float* __restrict__ refp,
                                                   __half* __restrict__ out) {
    const int tid  = threadIdx.x;
    const int g    = tid & 7;          // channel quad
    const int pair = tid >> 3;         // 0..31
    const int h    = pair & 7;
    const int n    = blockIdx.x * 4 + (pair >> 3);
    const int b    = n / LEN;
    const size_t rowb = (size_t)n * 640;

    // softmax over 16 (l,p) logits for this head (redundant across the 8 lanes)
    float lg[16];
    float mx = -1e30f;
#pragma unroll
    for (int s = 0; s < 16; ++s) {
        lg[s] = C1[rowb + 256 + h * 16 + s];
        mx = fmaxf(mx, lg[s]);
    }
    float sum = 0.f;
#pragma unroll
    for (int s = 0; s < 16; ++s) {
        lg[s] = expf(lg[s] - mx);
        sum += lg[s];
    }
    const float inv = 1.f / sum;

    const int Wi[4] = {64, 32, 16, 8};
    const int st[4] = {0, 4096, 5120, 5376};
    float4 acc = make_float4(0.f, 0.f, 0.f, 0.f);
    const int vbase_h = 384 + h * 32 + g * 4;

#pragma unroll
    for (int l = 0; l < 4; ++l) {
        const int   W  = Wi[l];
        const float Wf = (float)W;      // levels are square: Hl == Wl
        const float rx = refp[((size_t)n * 4 + l) * 2 + 0];
        const float ry = refp[((size_t)n * 4 + l) * 2 + 1];
#pragma unroll
        for (int p = 0; p < 4; ++p) {
            const float aw = lg[l * 4 + p] * inv;
            const float ox = C1[rowb + (size_t)(((h * 4 + l) * 4 + p) * 2 + 0)];
            const float oy = C1[rowb + (size_t)(((h * 4 + l) * 4 + p) * 2 + 1)];
            // match reference op order: loc = ref + off/W ; p = loc*W - 0.5
            const float lx = rx + ox / Wf;
            const float ly = ry + oy / Wf;
            const float px = lx * Wf - 0.5f;
            const float py = ly * Wf - 0.5f;
            const float x0f = floorf(px), y0f = floorf(py);
            const float wx1 = px - x0f, wy1 = py - y0f;
            const int x0 = (int)x0f, y0 = (int)y0f;
#pragma unroll
            for (int c = 0; c < 4; ++c) {
                const int dx = c & 1, dy = c >> 1;
                const int ix = x0 + dx, iy = y0 + dy;
                const float wgt = (dx ? wx1 : 1.f - wx1) * (dy ? wy1 : 1.f - wy1);
                const bool valid = (ix >= 0) && (ix < W) && (iy >= 0) && (iy < W);
                const int ixc = min(max(ix, 0), W - 1);
                const int iyc = min(max(iy, 0), W - 1);
                const int pos = st[l] + iyc * W + ixc;
                const float4 v = *(const float4*)&C1[((size_t)(b * LEN + pos)) * 640 + vbase_h];
                const float wa = valid ? (aw * wgt) : 0.f;
                acc.x = fmaf(wa, v.x, acc.x);
                acc.y = fmaf(wa, v.y, acc.y);
                acc.z = fmaf(wa, v.z, acc.z);
                acc.w = fmaf(wa, v.w, acc.w);
            }
        }
    }
    union { __half2 h[2]; uint2 u; } O;
    O.h[0] = __floats2half2_rn(acc.x, acc.y);
    O.h[1] = __floats2half2_rn(acc.z, acc.w);
    *(uint2*)&out[(size_t)n * 256 + h * 32 + g * 4] = O.u;
}

// ---------------- LayerNorm (wave per token): O = LN(Y + R) * g + b ----------------
template <bool WH>
__global__ __launch_bounds__(256) void ln_kernel(const float* __restrict__ Y,
                                                 const float* __restrict__ R,
                                                 const float* __restrict__ gm,
                                                 const float* __restrict__ bt,
                                                 float* __restrict__ O,
                                                 __half* __restrict__ OH) {
    const int wave = threadIdx.x >> 6, lane = threadIdx.x & 63;
    const int n = blockIdx.x * 4 + wave;
    const size_t base = (size_t)n * 256 + lane * 4;
    float4 y = *(const float4*)&Y[base];
    float4 r = *(const float4*)&R[base];
    float4 v = f4_add(y, r);
    float s = v.x + v.y + v.z + v.w;
#pragma unroll
    for (int m = 1; m < 64; m <<= 1) s += __shfl_xor(s, m, 64);
    const float mean = s * (1.f / 256.f);
    const float dx = v.x - mean, dy = v.y - mean, dz = v.z - mean, dw = v.w - mean;
    float ss = dx * dx + dy * dy + dz * dz + dw * dw;
#pragma unroll
    for (int m = 1; m < 64; m <<= 1) ss += __shfl_xor(ss, m, 64);
    const float rstd = rsqrtf(ss * (1.f / 256.f) + LEPS);
    const float4 g4 = *(const float4*)&gm[lane * 4];
    const float4 b4 = *(const float4*)&bt[lane * 4];
    float4 o;
    o.x = dx * rstd * g4.x + b4.x;
    o.y = dy * rstd * g4.y + b4.y;
    o.z = dz * rstd * g4.z + b4.z;
    o.w = dw * rstd * g4.w + b4.w;
    *(float4*)&O[base] = o;
    if (WH) {
        union { __half2 h[2]; uint2 u; } H;
        H.h[0] = __floats2half2_rn(o.x, o.y);
        H.h[1] = __floats2half2_rn(o.z, o.w);
        *(uint2*)&OH[base] = H.u;
    }
}

// ---------------- launch ----------------
extern "C" void kernel_launch(void* const* d_in, const int* in_sizes, int n_in,
                              void* d_out, int out_size, void* d_ws, size_t ws_size,
                              hipStream_t stream) {
    const float* src   = (const float*)d_in[0];
    const float* pos   = (const float*)d_in[1];
    const float* refp  = (const float*)d_in[2];
    const float* w_off  = (const float*)d_in[6];
    const float* b_off  = (const float*)d_in[7];
    const float* w_attn = (const float*)d_in[8];
    const float* b_attn = (const float*)d_in[9];
    const float* w_val  = (const float*)d_in[10];
    const float* b_val  = (const float*)d_in[11];
    const float* w_out  = (const float*)d_in[12];
    const float* b_out  = (const float*)d_in[13];
    const float* g1     = (const float*)d_in[14];
    const float* be1    = (const float*)d_in[15];
    const float* w1     = (const float*)d_in[16];
    const float* b1     = (const float*)d_in[17];
    const float* w2     = (const float*)d_in[18];
    const float* b2     = (const float*)d_in[19];
    const float* g2     = (const float*)d_in[20];
    const float* be2    = (const float*)d_in[21];

    float* ws = (float*)d_ws;
    // workspace layout (float offsets); total 42,156,672 floats ~= 168.6 MB
    float*  C1    = ws + 0;                       // [N,640] f32 ; ybuf/y2 alias after MSDA
    __half* msdah = (__half*)(ws + 13926400);     // [N,256] f16
    float*  xbuf  = ws + 16711680;                // [N,256] f32
    __half* xh    = (__half*)(ws + 22282240);     // [N,256] f16
    __half* hh    = (__half*)(ws + 25067520);     // [N,1024] f16
    __half* qh    = (__half*)(ws + 36208640);     // [N,256] f16
    __half* srch  = (__half*)(ws + 38993920);     // [N,256] f16
    __half* WcatT = (__half*)(ws + 41779200);     // [640][256] f16
    __half* woutT = (__half*)(ws + 41861120);     // [256][256] f16
    __half* w1T   = (__half*)(ws + 41893888);     // [1024][256] f16
    __half* w2T   = (__half*)(ws + 42024960);     // [256][1024] f16
    float*  bcat  = ws + 42156032;                // [640] f32
    float*  ybuf  = C1;

    pack_k<<<2944, 256, 0, stream>>>(w_off, w_attn, w_val, b_off, b_attn, b_val,
                                     w_out, w1, w2, WcatT, woutT, w1T, w2T, bcat);
    cvt_k<<<NTOK / 4, 256, 0, stream>>>(src, pos, qh, srch);

    // C1[N,640] = (q | src) @ Wcat + bcat   (col tiles < 384 use q)
    hgemm_k<false, true, false><<<dim3(5, 170), 256, 0, stream>>>(
        qh, srch, WcatT, bcat, C1, ((__half*)0), 640, 256, 384);

    msda_kernel<<<NTOK / 4, 256, 0, stream>>>(C1, refp, msdah);

    // ybuf = msda @ w_out + b_out
    hgemm_k<false, true, false><<<dim3(2, 170), 256, 0, stream>>>(
        msdah, msdah, woutT, b_out, ybuf, (__half*)0, 256, 256, 0);

    // x = LN(ybuf + src)  -> xbuf (f32) and xh (f16)
    ln_kernel<true><<<NTOK / 4, 256, 0, stream>>>(ybuf, src, g1, be1, xbuf, xh);

    // hh = relu(x @ w1 + b1)  (f16 only)
    hgemm_k<true, false, true><<<dim3(8, 170), 256, 0, stream>>>(
        xh, xh, w1T, b1, (float*)0, hh, DFF, 256, 0);

    // ybuf = hh @ w2 + b2
    hgemm_k<false, true, false><<<dim3(2, 170), 256, 0, stream>>>(
        hh, hh, w2T, b2, ybuf, (__half*)0, 256, DFF, 0);

    // out = LN(ybuf + xbuf)
    ln_kernel<false><<<NTOK / 4, 256, 0, stream>>>(ybuf, xbuf, g2, be2, (float*)d_out, (__half*)0);
}

// Round 3
// 301.158 us; speedup vs baseline: 2.3350x; 1.0748x over previous
//
#include <hip/hip_runtime.h>
#include <hip/hip_fp16.h>
#include <math.h>

// Problem constants (fixed by the reference)
#define LEN   5440          // 64*64 + 32*32 + 16*16 + 8*8
#define NTOK  21760         // B(4) * LEN
#define CDIM  256
#define HEADS 8
#define DFF   1024
#define LEPS  1e-5f

typedef __attribute__((ext_vector_type(8))) _Float16 f16x8;
typedef __attribute__((ext_vector_type(4))) float f32x4;

__device__ __forceinline__ float4 f4_add(float4 a, float4 b) {
    return make_float4(a.x + b.x, a.y + b.y, a.z + b.z, a.w + b.w);
}

// ---------------- pack: weights -> fp16, transposed to [N][K] ----------------
__global__ __launch_bounds__(256) void pack_k(const float* __restrict__ w_off,
                                              const float* __restrict__ w_attn,
                                              const float* __restrict__ w_val,
                                              const float* __restrict__ b_off,
                                              const float* __restrict__ b_attn,
                                              const float* __restrict__ b_val,
                                              const float* __restrict__ w_out,
                                              const float* __restrict__ w1,
                                              const float* __restrict__ w2,
                                              __half* __restrict__ WcatT,
                                              __half* __restrict__ woutT,
                                              __half* __restrict__ w1T,
                                              __half* __restrict__ w2T,
                                              float* __restrict__ bcat) {
    const int i = blockIdx.x * 256 + threadIdx.x;
    if (i < 163840) {                      // WcatT [c<640][k<256]
        const int c = i >> 8, k = i & 255;
        float v;
        if (c < 256)      v = w_off[k * 256 + c];
        else if (c < 384) v = w_attn[k * 128 + (c - 256)];
        else              v = w_val[k * 256 + (c - 384)];
        WcatT[i] = __float2half(v);
    } else if (i < 229376) {               // woutT [c<256][k<256]
        const int j = i - 163840, c = j >> 8, k = j & 255;
        woutT[j] = __float2half(w_out[k * 256 + c]);
    } else if (i < 491520) {               // w1T [c<1024][k<256]
        const int j = i - 229376, c = j >> 8, k = j & 255;
        w1T[j] = __float2half(w1[k * 1024 + c]);
    } else if (i < 753664) {               // w2T [c<256][k<1024]
        const int j = i - 491520, c = j >> 10, k = j & 1023;
        w2T[j] = __float2half(w2[k * 256 + c]);
    }
    if (i < 640) {
        bcat[i] = (i < 256) ? b_off[i] : (i < 384) ? b_attn[i - 256] : b_val[i - 384];
    }
}

// ---------------- fp16 MFMA GEMM: C[M,N] = A[M,K] @ Bt[N,K]^T + bias ----------------
// 128x128 tile, BK=32, 4 waves, each wave 64x64 via 4x4 frags of 16x16x32 MFMA.
// AF32: A is f32 (+A2f added for column tiles with bx*128 < colSwitch), converted
//       to fp16 during staging.
// OMODE: 0 = f32 out (stride NnF); 2 = relu + f16 out (stride NnH);
//        3 = split: bx*128 < colSwitch -> f32 (stride NnF), else f16 at
//            col-colSwitch (stride NnH).
template <bool AF32, int OMODE>
__global__ __launch_bounds__(256) void hgemm_k(const void* __restrict__ Ap,
                                               const float* __restrict__ A2f,
                                               const __half* __restrict__ Bt,
                                               const float* __restrict__ bias,
                                               float* __restrict__ Cf,
                                               __half* __restrict__ Ch,
                                               int NnF, int NnH, int K, int colSwitch) {
    __shared__ __half As[128][40];   // padded stride 40 halfs = 80 B
    __shared__ __half Bs[128][40];
    const int bx = blockIdx.x, by = blockIdx.y;
    const int tid = threadIdx.x;
    const int lane = tid & 63;
    const int wave = tid >> 6;
    const int wr = (wave >> 1) * 64;
    const int wc = (wave & 1) * 64;
    const bool useA2 = AF32 && (bx * 128 < colSwitch);

    const __half* Bbase = Bt + (size_t)(bx * 128) * K;

    // staging: thread t owns row t>>1, 16 contiguous elements at k-offset (t&1)*16
    const int srow = tid >> 1;
    const int sk = (tid & 1) * 16;

    f32x4 acc[4][4];
#pragma unroll
    for (int m = 0; m < 4; ++m)
#pragma unroll
        for (int n = 0; n < 4; ++n) acc[m][n] = (f32x4){0.f, 0.f, 0.f, 0.f};

    const int fr = lane & 15;
    const int fk = (lane >> 4) * 8;

    for (int k0 = 0; k0 < K; k0 += 32) {
        uint4 a0, a1;
        if (AF32) {
            const float* Af = (const float*)Ap + (size_t)(by * 128 + srow) * K + k0 + sk;
            float4 f0 = *(const float4*)(Af + 0);
            float4 f1 = *(const float4*)(Af + 4);
            float4 f2 = *(const float4*)(Af + 8);
            float4 f3 = *(const float4*)(Af + 12);
            if (useA2) {
                const float* Pf = A2f + (size_t)(by * 128 + srow) * K + k0 + sk;
                f0 = f4_add(f0, *(const float4*)(Pf + 0));
                f1 = f4_add(f1, *(const float4*)(Pf + 4));
                f2 = f4_add(f2, *(const float4*)(Pf + 8));
                f3 = f4_add(f3, *(const float4*)(Pf + 12));
            }
            union { __half2 h[8]; uint4 u[2]; } cv;
            cv.h[0] = __floats2half2_rn(f0.x, f0.y);
            cv.h[1] = __floats2half2_rn(f0.z, f0.w);
            cv.h[2] = __floats2half2_rn(f1.x, f1.y);
            cv.h[3] = __floats2half2_rn(f1.z, f1.w);
            cv.h[4] = __floats2half2_rn(f2.x, f2.y);
            cv.h[5] = __floats2half2_rn(f2.z, f2.w);
            cv.h[6] = __floats2half2_rn(f3.x, f3.y);
            cv.h[7] = __floats2half2_rn(f3.z, f3.w);
            a0 = cv.u[0];
            a1 = cv.u[1];
        } else {
            const __half* Ah = (const __half*)Ap + (size_t)(by * 128 + srow) * K + k0 + sk;
            a0 = *(const uint4*)(Ah + 0);
            a1 = *(const uint4*)(Ah + 8);
        }
        const uint4 b0 = *(const uint4*)&Bbase[(size_t)srow * K + k0 + sk];
        const uint4 b1 = *(const uint4*)&Bbase[(size_t)srow * K + k0 + sk + 8];
        __syncthreads();   // previous iteration's reads done before overwrite
        *(uint4*)&As[srow][sk]     = a0;
        *(uint4*)&As[srow][sk + 8] = a1;
        *(uint4*)&Bs[srow][sk]     = b0;
        *(uint4*)&Bs[srow][sk + 8] = b1;
        __syncthreads();
        f16x8 af[4], bf[4];
#pragma unroll
        for (int m = 0; m < 4; ++m) af[m] = *(const f16x8*)&As[wr + m * 16 + fr][fk];
#pragma unroll
        for (int n = 0; n < 4; ++n) bf[n] = *(const f16x8*)&Bs[wc + n * 16 + fr][fk];
#pragma unroll
        for (int m = 0; m < 4; ++m)
#pragma unroll
            for (int n = 0; n < 4; ++n)
                acc[m][n] = __builtin_amdgcn_mfma_f32_16x16x32_f16(af[m], bf[n], acc[m][n], 0, 0, 0);
    }

    // C/D layout (m89): col = lane&15, row = (lane>>4)*4 + reg
    const int rowb = by * 128 + wr + (lane >> 4) * 4;
    const int colb = bx * 128 + wc + fr;
    float bn[4];
#pragma unroll
    for (int n = 0; n < 4; ++n) bn[n] = bias[colb + n * 16];
    const bool vhalf = (OMODE == 2) || (OMODE == 3 && bx * 128 >= colSwitch);
    const int colh = (OMODE == 3) ? (colb - colSwitch) : colb;
#pragma unroll
    for (int m = 0; m < 4; ++m) {
#pragma unroll
        for (int r = 0; r < 4; ++r) {
            const int row = rowb + m * 16 + r;
#pragma unroll
            for (int n = 0; n < 4; ++n) {
                float v = acc[m][n][r] + bn[n];
                if (OMODE == 2) v = fmaxf(v, 0.f);
                if (vhalf) Ch[(size_t)row * NnH + colh + n * 16] = __float2half(v);
                else       Cf[(size_t)row * NnF + colb + n * 16] = v;
            }
        }
    }
}

// ---------------- MSDA: two-phase (descriptor prep in LDS, then fp16 gather) ----
// C1a row layout per token n: [0,256) offsets, [256,384) attn logits (f32, stride 384)
// Vh: [N,256] fp16 value. Block = 256 threads = 2 tokens * 8 heads * 16 lanes.
__global__ __launch_bounds__(256) void msda_kernel(const float* __restrict__ C1a,
                                                   const __half* __restrict__ Vh,
                                                   const float* __restrict__ refp,
                                                   __half* __restrict__ out) {
    __shared__ int   sIdx[16][17][4];   // padded: 4 groups/wave land on distinct banks
    __shared__ float sW[16][17][4];
    const int tid = threadIdx.x;
    const int gi = tid >> 4;           // (token,head) group 0..15
    const int si = tid & 15;           // sample id (phase 1) / lane id (phase 2)
    const int n = blockIdx.x * 2 + (gi >> 3);
    const int h = gi & 7;
    const int b = n / LEN;

    // ---- phase 1: one lane per (l,p) sample computes softmax + corner descriptors
    {
        const int l = si >> 2, p = si & 3;
        const float lg = C1a[(size_t)n * 384 + 256 + h * 16 + si];
        float mx = lg;
#pragma unroll
        for (int m = 1; m < 16; m <<= 1) mx = fmaxf(mx, __shfl_xor(mx, m, 16));
        const float e = expf(lg - mx);
        float sum = e;
#pragma unroll
        for (int m = 1; m < 16; m <<= 1) sum += __shfl_xor(sum, m, 16);
        const float aw = e / sum;

        const int Wi[4] = {64, 32, 16, 8};
        const int st[4] = {0, 4096, 5120, 5376};
        const int W = Wi[l];
        const float Wf = (float)W;
        const float rx = refp[((size_t)n * 4 + l) * 2 + 0];
        const float ry = refp[((size_t)n * 4 + l) * 2 + 1];
        const float ox = C1a[(size_t)n * 384 + (((h * 4 + l) * 4 + p) * 2 + 0)];
        const float oy = C1a[(size_t)n * 384 + (((h * 4 + l) * 4 + p) * 2 + 1)];
        // match reference op order: loc = ref + off/W ; px = loc*W - 0.5
        const float lx = rx + ox / Wf;
        const float ly = ry + oy / Wf;
        const float px = lx * Wf - 0.5f;
        const float py = ly * Wf - 0.5f;
        const float x0f = floorf(px), y0f = floorf(py);
        const float wx1 = px - x0f, wy1 = py - y0f;
        const int x0 = (int)x0f, y0 = (int)y0f;
#pragma unroll
        for (int c = 0; c < 4; ++c) {
            const int dx = c & 1, dy = c >> 1;
            const int ix = x0 + dx, iy = y0 + dy;
            const float wgt = (dx ? wx1 : 1.f - wx1) * (dy ? wy1 : 1.f - wy1);
            const bool valid = (ix >= 0) && (ix < W) && (iy >= 0) && (iy < W);
            const int ixc = min(max(ix, 0), W - 1);
            const int iyc = min(max(iy, 0), W - 1);
            const int pos = st[l] + iyc * W + ixc;
            sIdx[gi][si][c] = ((b * LEN + pos) << 8) + h * 32;   // element index into Vh
            sW[gi][si][c] = valid ? (aw * wgt) : 0.f;
        }
    }
    __syncthreads();

    // ---- phase 2: 16 lanes per (n,h), each accumulates 2 channels over 64 corners
    float accx = 0.f, accy = 0.f;
    const int ch = si * 2;
#pragma unroll
    for (int s = 0; s < 16; ++s) {
        const int4   idx = *(const int4*)&sIdx[gi][s][0];
        const float4 w   = *(const float4*)&sW[gi][s][0];
        {
            const float2 v = __half22float2(*(const __half2*)&Vh[idx.x + ch]);
            accx = fmaf(w.x, v.x, accx); accy = fmaf(w.x, v.y, accy);
        }
        {
            const float2 v = __half22float2(*(const __half2*)&Vh[idx.y + ch]);
            accx = fmaf(w.y, v.x, accx); accy = fmaf(w.y, v.y, accy);
        }
        {
            const float2 v = __half22float2(*(const __half2*)&Vh[idx.z + ch]);
            accx = fmaf(w.z, v.x, accx); accy = fmaf(w.z, v.y, accy);
        }
        {
            const float2 v = __half22float2(*(const __half2*)&Vh[idx.w + ch]);
            accx = fmaf(w.w, v.x, accx); accy = fmaf(w.w, v.y, accy);
        }
    }
    union { __half2 h2; unsigned u; } O;
    O.h2 = __floats2half2_rn(accx, accy);
    *(unsigned*)&out[(size_t)n * 256 + h * 32 + ch] = O.u;
}

// ---------------- LayerNorm (wave per token): O = LN(Y + R) * g + b ----------------
template <bool WH>
__global__ __launch_bounds__(256) void ln_kernel(const float* __restrict__ Y,
                                                 const float* __restrict__ R,
                                                 const float* __restrict__ gm,
                                                 const float* __restrict__ bt,
                                                 float* __restrict__ O,
                                                 __half* __restrict__ OH) {
    const int wave = threadIdx.x >> 6, lane = threadIdx.x & 63;
    const int n = blockIdx.x * 4 + wave;
    const size_t base = (size_t)n * 256 + lane * 4;
    float4 y = *(const float4*)&Y[base];
    float4 r = *(const float4*)&R[base];
    float4 v = f4_add(y, r);
    float s = v.x + v.y + v.z + v.w;
#pragma unroll
    for (int m = 1; m < 64; m <<= 1) s += __shfl_xor(s, m, 64);
    const float mean = s * (1.f / 256.f);
    const float dx = v.x - mean, dy = v.y - mean, dz = v.z - mean, dw = v.w - mean;
    float ss = dx * dx + dy * dy + dz * dz + dw * dw;
#pragma unroll
    for (int m = 1; m < 64; m <<= 1) ss += __shfl_xor(ss, m, 64);
    const float rstd = rsqrtf(ss * (1.f / 256.f) + LEPS);
    const float4 g4 = *(const float4*)&gm[lane * 4];
    const float4 b4 = *(const float4*)&bt[lane * 4];
    float4 o;
    o.x = dx * rstd * g4.x + b4.x;
    o.y = dy * rstd * g4.y + b4.y;
    o.z = dz * rstd * g4.z + b4.z;
    o.w = dw * rstd * g4.w + b4.w;
    *(float4*)&O[base] = o;
    if (WH) {
        union { __half2 h[2]; uint2 u; } Hh;
        Hh.h[0] = __floats2half2_rn(o.x, o.y);
        Hh.h[1] = __floats2half2_rn(o.z, o.w);
        *(uint2*)&OH[base] = Hh.u;
    }
}

// ---------------- launch ----------------
extern "C" void kernel_launch(void* const* d_in, const int* in_sizes, int n_in,
                              void* d_out, int out_size, void* d_ws, size_t ws_size,
                              hipStream_t stream) {
    const float* src   = (const float*)d_in[0];
    const float* pos   = (const float*)d_in[1];
    const float* refp  = (const float*)d_in[2];
    const float* w_off  = (const float*)d_in[6];
    const float* b_off  = (const float*)d_in[7];
    const float* w_attn = (const float*)d_in[8];
    const float* b_attn = (const float*)d_in[9];
    const float* w_val  = (const float*)d_in[10];
    const float* b_val  = (const float*)d_in[11];
    const float* w_out  = (const float*)d_in[12];
    const float* b_out  = (const float*)d_in[13];
    const float* g1     = (const float*)d_in[14];
    const float* be1    = (const float*)d_in[15];
    const float* w1     = (const float*)d_in[16];
    const float* b1     = (const float*)d_in[17];
    const float* w2     = (const float*)d_in[18];
    const float* b2     = (const float*)d_in[19];
    const float* g2     = (const float*)d_in[20];
    const float* be2    = (const float*)d_in[21];

    float* ws = (float*)d_ws;
    // workspace layout (float offsets); total ~33.8M floats ~= 135 MB
    float*  C1a   = ws + 0;                       // [N,384] f32 off|logits; ybuf alias
    __half* Vh    = (__half*)(ws + 8355840);      // [N,256] f16 value
    __half* msdah = (__half*)(ws + 11141120);     // [N,256] f16
    float*  xbuf  = ws + 13926400;                // [N,256] f32
    __half* xh    = (__half*)(ws + 19496960);     // [N,256] f16
    __half* hh    = (__half*)(ws + 22282240);     // [N,1024] f16
    __half* WcatT = (__half*)(ws + 33423360);     // [640][256] f16
    __half* woutT = (__half*)(ws + 33505280);     // [256][256] f16
    __half* w1T   = (__half*)(ws + 33538048);     // [1024][256] f16
    __half* w2T   = (__half*)(ws + 33669120);     // [256][1024] f16
    float*  bcat  = ws + 33800192;                // [640] f32
    float*  ybuf  = C1a;                          // C1a dead after msda

    pack_k<<<2944, 256, 0, stream>>>(w_off, w_attn, w_val, b_off, b_attn, b_val,
                                     w_out, w1, w2, WcatT, woutT, w1T, w2T, bcat);

    // GEMM1: [N,640] = (half(src+pos) | half(src)) @ Wcat + bcat
    //   cols [0,384) -> C1a f32 ; cols [384,640) -> Vh f16
    hgemm_k<true, 3><<<dim3(5, 170), 256, 0, stream>>>(
        (const void*)src, pos, WcatT, bcat, C1a, Vh, 384, 256, 256, 384);

    msda_kernel<<<NTOK / 2, 256, 0, stream>>>(C1a, Vh, refp, msdah);

    // ybuf = msda @ w_out + b_out
    hgemm_k<false, 0><<<dim3(2, 170), 256, 0, stream>>>(
        (const void*)msdah, nullptr, woutT, b_out, ybuf, nullptr, 256, 256, 256, 0);

    // x = LN(ybuf + src) -> xbuf (f32) and xh (f16)
    ln_kernel<true><<<NTOK / 4, 256, 0, stream>>>(ybuf, src, g1, be1, xbuf, xh);

    // hh = relu(x @ w1 + b1)  (f16)
    hgemm_k<false, 2><<<dim3(8, 170), 256, 0, stream>>>(
        (const void*)xh, nullptr, w1T, b1, nullptr, hh, 1024, 1024, 256, 0);

    // ybuf = hh @ w2 + b2
    hgemm_k<false, 0><<<dim3(2, 170), 256, 0, stream>>>(
        (const void*)hh, nullptr, w2T, b2, ybuf, nullptr, 256, 256, 1024, 0);

    // out = LN(ybuf + xbuf)
    ln_kernel<false><<<NTOK / 4, 256, 0, stream>>>(ybuf, xbuf, g2, be2, (float*)d_out, nullptr);
}

// Round 4
// 284.987 us; speedup vs baseline: 2.4675x; 1.0567x over previous
//
#include <hip/hip_runtime.h>
#include <hip/hip_fp16.h>
#include <math.h>

// Problem constants (fixed by the reference)
#define LEN   5440          // 64*64 + 32*32 + 16*16 + 8*8
#define NTOK  21760         // B(4) * LEN
#define DFF   1024
#define LEPS  1e-5f

typedef __attribute__((ext_vector_type(8))) _Float16 f16x8;
typedef __attribute__((ext_vector_type(4))) float f32x4;

__device__ __forceinline__ float4 f4_add(float4 a, float4 b) {
    return make_float4(a.x + b.x, a.y + b.y, a.z + b.z, a.w + b.w);
}

// Bijective XCD-chunk swizzle (m204): dispatch-linear id -> tile id such that
// each XCD (= lin%8 round-robin) owns a contiguous tile chunk.
__device__ __forceinline__ int swz8(int lin, int nwg) {
    const int q = nwg >> 3, r = nwg & 7;
    const int x = lin & 7, j = lin >> 3;
    return (x < r ? x * (q + 1) : r * (q + 1) + (x - r) * q) + j;
}

// ---------------- pack: weights -> fp16, transposed to [N][K] ----------------
__global__ __launch_bounds__(256) void pack_k(const float* __restrict__ w_off,
                                              const float* __restrict__ w_attn,
                                              const float* __restrict__ w_val,
                                              const float* __restrict__ b_off,
                                              const float* __restrict__ b_attn,
                                              const float* __restrict__ b_val,
                                              const float* __restrict__ w_out,
                                              const float* __restrict__ w1,
                                              const float* __restrict__ w2,
                                              __half* __restrict__ WcatT,
                                              __half* __restrict__ woutT,
                                              __half* __restrict__ w1T,
                                              __half* __restrict__ w2T,
                                              float* __restrict__ bcat) {
    const int i = blockIdx.x * 256 + threadIdx.x;
    if (i < 163840) {                      // WcatT [c<640][k<256]
        const int c = i >> 8, k = i & 255;
        float v;
        if (c < 256)      v = w_off[k * 256 + c];
        else if (c < 384) v = w_attn[k * 128 + (c - 256)];
        else              v = w_val[k * 256 + (c - 384)];
        WcatT[i] = __float2half(v);
    } else if (i < 229376) {               // woutT [c<256][k<256]
        const int j = i - 163840, c = j >> 8, k = j & 255;
        woutT[j] = __float2half(w_out[k * 256 + c]);
    } else if (i < 491520) {               // w1T [c<1024][k<256]
        const int j = i - 229376, c = j >> 8, k = j & 255;
        w1T[j] = __float2half(w1[k * 1024 + c]);
    } else if (i < 753664) {               // w2T [c<256][k<1024]
        const int j = i - 491520, c = j >> 10, k = j & 1023;
        w2T[j] = __float2half(w2[k * 256 + c]);
    }
    if (i < 640) {
        bcat[i] = (i < 256) ? b_off[i] : (i < 384) ? b_attn[i - 256] : b_val[i - 384];
    }
}

// ---------------- fp16 MFMA GEMM: C[M,N] = A[M,K] @ Bt[N,K]^T + bias ----------------
// 128x128 tile, BK=32, 4 waves, each wave 64x64 via 4x4 frags of 16x16x32 MFMA.
// Register-prefetch pipeline: next K-step's global loads issue right after the
// LDS-store barrier; vmcnt wait lands at the NEXT iteration's store, hidden
// under ds_read + MFMA of the current step.
// AF32: A is f32 (+A2f added when bx*128 < colSwitch), converted at store time.
// OMODE: 0 = f32 out; 2 = relu + f16 out; 3 = split f32 / f16-at-(col-colSwitch).
template <bool AF32, int OMODE>
__global__ __launch_bounds__(256) void hgemm_k(const void* __restrict__ Ap,
                                               const float* __restrict__ A2f,
                                               const __half* __restrict__ Bt,
                                               const float* __restrict__ bias,
                                               float* __restrict__ Cf,
                                               __half* __restrict__ Ch,
                                               int NnF, int NnH, int K, int colSwitch) {
    __shared__ __half As[128][40];   // padded stride 40 halfs = 80 B
    __shared__ __half Bs[128][40];
    const int nbx = gridDim.x;
    const int nwg = nbx * gridDim.y;
    const int tile = swz8(blockIdx.y * nbx + blockIdx.x, nwg);
    const int bx = tile % nbx, by = tile / nbx;   // bx fastest: same-A tiles adjacent

    const int tid = threadIdx.x;
    const int lane = tid & 63;
    const int wave = tid >> 6;
    const int wr = (wave >> 1) * 64;
    const int wc = (wave & 1) * 64;
    const bool useA2 = AF32 && (bx * 128 < colSwitch);

    // staging: thread t owns row t>>1, 16 contiguous elements at k-offset (t&1)*16
    const int srow = tid >> 1;
    const int sk = (tid & 1) * 16;

    const __half* Brow   = Bt + (size_t)(bx * 128 + srow) * K + sk;
    const float*  Afrow  = AF32 ? ((const float*)Ap + (size_t)(by * 128 + srow) * K + sk) : nullptr;
    const float*  Pfrow  = useA2 ? (A2f + (size_t)(by * 128 + srow) * K + sk) : nullptr;
    const __half* Ahrow  = AF32 ? nullptr : ((const __half*)Ap + (size_t)(by * 128 + srow) * K + sk);

    f32x4 acc[4][4];
#pragma unroll
    for (int m = 0; m < 4; ++m)
#pragma unroll
        for (int n = 0; n < 4; ++n) acc[m][n] = (f32x4){0.f, 0.f, 0.f, 0.f};

    const int fr = lane & 15;
    const int fk = (lane >> 4) * 8;

    uint4 a0, a1, b0, b1;
    float4 ra0, ra1, ra2, ra3, rp0, rp1, rp2, rp3;

    // prologue: issue loads for k0 = 0
    if (AF32) {
        ra0 = *(const float4*)(Afrow + 0);
        ra1 = *(const float4*)(Afrow + 4);
        ra2 = *(const float4*)(Afrow + 8);
        ra3 = *(const float4*)(Afrow + 12);
        if (useA2) {
            rp0 = *(const float4*)(Pfrow + 0);
            rp1 = *(const float4*)(Pfrow + 4);
            rp2 = *(const float4*)(Pfrow + 8);
            rp3 = *(const float4*)(Pfrow + 12);
        }
    } else {
        a0 = *(const uint4*)(Ahrow + 0);
        a1 = *(const uint4*)(Ahrow + 8);
    }
    b0 = *(const uint4*)(Brow + 0);
    b1 = *(const uint4*)(Brow + 8);

    for (int k0 = 0; k0 < K; k0 += 32) {
        __syncthreads();   // all lanes finished reading LDS from previous step
        if (AF32) {
            float4 f0 = ra0, f1 = ra1, f2 = ra2, f3 = ra3;
            if (useA2) {
                f0 = f4_add(f0, rp0);
                f1 = f4_add(f1, rp1);
                f2 = f4_add(f2, rp2);
                f3 = f4_add(f3, rp3);
            }
            union { __half2 h[8]; uint4 u[2]; } cv;
            cv.h[0] = __floats2half2_rn(f0.x, f0.y);
            cv.h[1] = __floats2half2_rn(f0.z, f0.w);
            cv.h[2] = __floats2half2_rn(f1.x, f1.y);
            cv.h[3] = __floats2half2_rn(f1.z, f1.w);
            cv.h[4] = __floats2half2_rn(f2.x, f2.y);
            cv.h[5] = __floats2half2_rn(f2.z, f2.w);
            cv.h[6] = __floats2half2_rn(f3.x, f3.y);
            cv.h[7] = __floats2half2_rn(f3.z, f3.w);
            a0 = cv.u[0];
            a1 = cv.u[1];
        }
        *(uint4*)&As[srow][sk]     = a0;
        *(uint4*)&As[srow][sk + 8] = a1;
        *(uint4*)&Bs[srow][sk]     = b0;
        *(uint4*)&Bs[srow][sk + 8] = b1;
        __syncthreads();

        const int kn = k0 + 32;
        if (kn < K) {      // uniform branch: prefetch next step into regs
            if (AF32) {
                ra0 = *(const float4*)(Afrow + kn + 0);
                ra1 = *(const float4*)(Afrow + kn + 4);
                ra2 = *(const float4*)(Afrow + kn + 8);
                ra3 = *(const float4*)(Afrow + kn + 12);
                if (useA2) {
                    rp0 = *(const float4*)(Pfrow + kn + 0);
                    rp1 = *(const float4*)(Pfrow + kn + 4);
                    rp2 = *(const float4*)(Pfrow + kn + 8);
                    rp3 = *(const float4*)(Pfrow + kn + 12);
                }
            } else {
                a0 = *(const uint4*)(Ahrow + kn + 0);
                a1 = *(const uint4*)(Ahrow + kn + 8);
            }
            b0 = *(const uint4*)(Brow + kn + 0);
            b1 = *(const uint4*)(Brow + kn + 8);
        }

        f16x8 af[4], bf[4];
#pragma unroll
        for (int m = 0; m < 4; ++m) af[m] = *(const f16x8*)&As[wr + m * 16 + fr][fk];
#pragma unroll
        for (int n = 0; n < 4; ++n) bf[n] = *(const f16x8*)&Bs[wc + n * 16 + fr][fk];
#pragma unroll
        for (int m = 0; m < 4; ++m)
#pragma unroll
            for (int n = 0; n < 4; ++n)
                acc[m][n] = __builtin_amdgcn_mfma_f32_16x16x32_f16(af[m], bf[n], acc[m][n], 0, 0, 0);
    }

    // C/D layout (m89): col = lane&15, row = (lane>>4)*4 + reg
    const int rowb = by * 128 + wr + (lane >> 4) * 4;
    const int colb = bx * 128 + wc + fr;
    float bn[4];
#pragma unroll
    for (int n = 0; n < 4; ++n) bn[n] = bias[colb + n * 16];
    const bool vhalf = (OMODE == 2) || (OMODE == 3 && bx * 128 >= colSwitch);
    const int colh = (OMODE == 3) ? (colb - colSwitch) : colb;
#pragma unroll
    for (int m = 0; m < 4; ++m) {
#pragma unroll
        for (int r = 0; r < 4; ++r) {
            const int row = rowb + m * 16 + r;
#pragma unroll
            for (int n = 0; n < 4; ++n) {
                float v = acc[m][n][r] + bn[n];
                if (OMODE == 2) v = fmaxf(v, 0.f);
                if (vhalf) Ch[(size_t)row * NnH + colh + n * 16] = __float2half(v);
                else       Cf[(size_t)row * NnF + colb + n * 16] = v;
            }
        }
    }
}

// ---------------- MSDA: two-phase (descriptor prep in LDS, then fp16 gather) ----
// C1a row layout per token n: [0,256) offsets, [256,384) attn logits (f32, stride 384)
// Vh: [N,256] fp16 value. Block = 256 threads = 2 tokens * 8 heads * 16 lanes.
// Phase 2 re-lane: lane si -> corner-block (si>>2: 16 corners) x channel-octet
// (si&3: 8 fp16 ch, one dwordx4 per corner). Byte offsets precomputed in phase 1
// so each load is SGPR-base + 32-bit voffset; fmaf(w,(float)h,acc) -> v_fma_mix.
__global__ __launch_bounds__(256) void msda_kernel(const float* __restrict__ C1a,
                                                   const __half* __restrict__ Vh,
                                                   const float* __restrict__ refp,
                                                   __half* __restrict__ out) {
    __shared__ int   sOff[16][17][4];   // byte offsets into Vh (row*512 + h*64)
    __shared__ float sW[16][17][4];
    const int tid = threadIdx.x;
    const int gi = tid >> 4;           // (token,head) group 0..15
    const int si = tid & 15;
    const int tile = swz8(blockIdx.x, gridDim.x);   // NTOK/2 divisible by 8
    const int n = tile * 2 + (gi >> 3);
    const int h = gi & 7;
    const int b = n / LEN;

    // ---- phase 1: one lane per (l,p) sample computes softmax + corner descriptors
    {
        const int l = si >> 2, p = si & 3;
        const float lg = C1a[(size_t)n * 384 + 256 + h * 16 + si];
        float mx = lg;
#pragma unroll
        for (int m = 1; m < 16; m <<= 1) mx = fmaxf(mx, __shfl_xor(mx, m, 16));
        const float e = expf(lg - mx);
        float sum = e;
#pragma unroll
        for (int m = 1; m < 16; m <<= 1) sum += __shfl_xor(sum, m, 16);
        const float aw = e / sum;

        const int Wi[4] = {64, 32, 16, 8};
        const int st[4] = {0, 4096, 5120, 5376};
        const int W = Wi[l];
        const float Wf = (float)W;
        const float rx = refp[((size_t)n * 4 + l) * 2 + 0];
        const float ry = refp[((size_t)n * 4 + l) * 2 + 1];
        const float ox = C1a[(size_t)n * 384 + (((h * 4 + l) * 4 + p) * 2 + 0)];
        const float oy = C1a[(size_t)n * 384 + (((h * 4 + l) * 4 + p) * 2 + 1)];
        // match reference op order: loc = ref + off/W ; px = loc*W - 0.5
        const float lx = rx + ox / Wf;
        const float ly = ry + oy / Wf;
        const float px = lx * Wf - 0.5f;
        const float py = ly * Wf - 0.5f;
        const float x0f = floorf(px), y0f = floorf(py);
        const float wx1 = px - x0f, wy1 = py - y0f;
        const int x0 = (int)x0f, y0 = (int)y0f;
#pragma unroll
        for (int c = 0; c < 4; ++c) {
            const int dx = c & 1, dy = c >> 1;
            const int ix = x0 + dx, iy = y0 + dy;
            const float wgt = (dx ? wx1 : 1.f - wx1) * (dy ? wy1 : 1.f - wy1);
            const bool valid = (ix >= 0) && (ix < W) && (iy >= 0) && (iy < W);
            const int ixc = min(max(ix, 0), W - 1);
            const int iyc = min(max(iy, 0), W - 1);
            const int pos = st[l] + iyc * W + ixc;
            sOff[gi][si][c] = ((b * LEN + pos) << 9) + (h << 6);   // BYTE offset
            sW[gi][si][c] = valid ? (aw * wgt) : 0.f;
        }
    }
    __syncthreads();

    // ---- phase 2: 16 corners x 8 channels per lane, dwordx4 loads, fma_mix accum
    const int cbyte = (si & 3) * 16;    // channel-octet byte offset within h-slice
    const int sb = (si >> 2) * 4;       // first sample of this lane's corner block
    float acc[8];
#pragma unroll
    for (int j = 0; j < 8; ++j) acc[j] = 0.f;
    const char* Vb = (const char*)Vh;
#pragma unroll
    for (int t = 0; t < 4; ++t) {
        const int s = sb + t;
        const int4   off = *(const int4*)&sOff[gi][s][0];
        const float4 w   = *(const float4*)&sW[gi][s][0];
        const f16x8 v0 = *(const f16x8*)(Vb + off.x + cbyte);
        const f16x8 v1 = *(const f16x8*)(Vb + off.y + cbyte);
        const f16x8 v2 = *(const f16x8*)(Vb + off.z + cbyte);
        const f16x8 v3 = *(const f16x8*)(Vb + off.w + cbyte);
#pragma unroll
        for (int j = 0; j < 8; ++j) {
            acc[j] = fmaf(w.x, (float)v0[j], acc[j]);
            acc[j] = fmaf(w.y, (float)v1[j], acc[j]);
            acc[j] = fmaf(w.z, (float)v2[j], acc[j]);
            acc[j] = fmaf(w.w, (float)v3[j], acc[j]);
        }
    }
    // reduce the 4 corner-blocks (lanes si, si^4, si^8 share the channel-octet)
#pragma unroll
    for (int j = 0; j < 8; ++j) {
        acc[j] += __shfl_xor(acc[j], 4, 64);
        acc[j] += __shfl_xor(acc[j], 8, 64);
    }
    if (si < 4) {
        union { __half2 h2[4]; uint4 u; } O;
        O.h2[0] = __floats2half2_rn(acc[0], acc[1]);
        O.h2[1] = __floats2half2_rn(acc[2], acc[3]);
        O.h2[2] = __floats2half2_rn(acc[4], acc[5]);
        O.h2[3] = __floats2half2_rn(acc[6], acc[7]);
        *(uint4*)&out[(size_t)n * 256 + h * 32 + si * 8] = O.u;
    }
}

// ---------------- LayerNorm (wave per token): O = LN(Y + R) * g + b ----------------
template <bool WH>
__global__ __launch_bounds__(256) void ln_kernel(const float* __restrict__ Y,
                                                 const float* __restrict__ R,
                                                 const float* __restrict__ gm,
                                                 const float* __restrict__ bt,
                                                 float* __restrict__ O,
                                                 __half* __restrict__ OH) {
    const int wave = threadIdx.x >> 6, lane = threadIdx.x & 63;
    const int n = blockIdx.x * 4 + wave;
    const size_t base = (size_t)n * 256 + lane * 4;
    float4 y = *(const float4*)&Y[base];
    float4 r = *(const float4*)&R[base];
    float4 v = f4_add(y, r);
    float s = v.x + v.y + v.z + v.w;
#pragma unroll
    for (int m = 1; m < 64; m <<= 1) s += __shfl_xor(s, m, 64);
    const float mean = s * (1.f / 256.f);
    const float dx = v.x - mean, dy = v.y - mean, dz = v.z - mean, dw = v.w - mean;
    float ss = dx * dx + dy * dy + dz * dz + dw * dw;
#pragma unroll
    for (int m = 1; m < 64; m <<= 1) ss += __shfl_xor(ss, m, 64);
    const float rstd = rsqrtf(ss * (1.f / 256.f) + LEPS);
    const float4 g4 = *(const float4*)&gm[lane * 4];
    const float4 b4 = *(const float4*)&bt[lane * 4];
    float4 o;
    o.x = dx * rstd * g4.x + b4.x;
    o.y = dy * rstd * g4.y + b4.y;
    o.z = dz * rstd * g4.z + b4.z;
    o.w = dw * rstd * g4.w + b4.w;
    *(float4*)&O[base] = o;
    if (WH) {
        union { __half2 h[2]; uint2 u; } Hh;
        Hh.h[0] = __floats2half2_rn(o.x, o.y);
        Hh.h[1] = __floats2half2_rn(o.z, o.w);
        *(uint2*)&OH[base] = Hh.u;
    }
}

// ---------------- launch ----------------
extern "C" void kernel_launch(void* const* d_in, const int* in_sizes, int n_in,
                              void* d_out, int out_size, void* d_ws, size_t ws_size,
                              hipStream_t stream) {
    const float* src   = (const float*)d_in[0];
    const float* pos   = (const float*)d_in[1];
    const float* refp  = (const float*)d_in[2];
    const float* w_off  = (const float*)d_in[6];
    const float* b_off  = (const float*)d_in[7];
    const float* w_attn = (const float*)d_in[8];
    const float* b_attn = (const float*)d_in[9];
    const float* w_val  = (const float*)d_in[10];
    const float* b_val  = (const float*)d_in[11];
    const float* w_out  = (const float*)d_in[12];
    const float* b_out  = (const float*)d_in[13];
    const float* g1     = (const float*)d_in[14];
    const float* be1    = (const float*)d_in[15];
    const float* w1     = (const float*)d_in[16];
    const float* b1     = (const float*)d_in[17];
    const float* w2     = (const float*)d_in[18];
    const float* b2     = (const float*)d_in[19];
    const float* g2     = (const float*)d_in[20];
    const float* be2    = (const float*)d_in[21];

    float* ws = (float*)d_ws;
    // workspace layout (float offsets); total ~33.8M floats ~= 135 MB
    float*  C1a   = ws + 0;                       // [N,384] f32 off|logits; ybuf alias
    __half* Vh    = (__half*)(ws + 8355840);      // [N,256] f16 value
    __half* msdah = (__half*)(ws + 11141120);     // [N,256] f16
    float*  xbuf  = ws + 13926400;                // [N,256] f32
    __half* xh    = (__half*)(ws + 19496960);     // [N,256] f16
    __half* hh    = (__half*)(ws + 22282240);     // [N,1024] f16
    __half* WcatT = (__half*)(ws + 33423360);     // [640][256] f16
    __half* woutT = (__half*)(ws + 33505280);     // [256][256] f16
    __half* w1T   = (__half*)(ws + 33538048);     // [1024][256] f16
    __half* w2T   = (__half*)(ws + 33669120);     // [256][1024] f16
    float*  bcat  = ws + 33800192;                // [640] f32
    float*  ybuf  = C1a;                          // C1a dead after msda

    pack_k<<<2944, 256, 0, stream>>>(w_off, w_attn, w_val, b_off, b_attn, b_val,
                                     w_out, w1, w2, WcatT, woutT, w1T, w2T, bcat);

    // GEMM1: [N,640] = (half(src+pos) | half(src)) @ Wcat + bcat
    //   cols [0,384) -> C1a f32 ; cols [384,640) -> Vh f16
    hgemm_k<true, 3><<<dim3(5, 170), 256, 0, stream>>>(
        (const void*)src, pos, WcatT, bcat, C1a, Vh, 384, 256, 256, 384);

    msda_kernel<<<NTOK / 2, 256, 0, stream>>>(C1a, Vh, refp, msdah);

    // ybuf = msda @ w_out + b_out
    hgemm_k<false, 0><<<dim3(2, 170), 256, 0, stream>>>(
        (const void*)msdah, nullptr, woutT, b_out, ybuf, nullptr, 256, 256, 256, 0);

    // x = LN(ybuf + src) -> xbuf (f32) and xh (f16)
    ln_kernel<true><<<NTOK / 4, 256, 0, stream>>>(ybuf, src, g1, be1, xbuf, xh);

    // hh = relu(x @ w1 + b1)  (f16)
    hgemm_k<false, 2><<<dim3(8, 170), 256, 0, stream>>>(
        (const void*)xh, nullptr, w1T, b1, nullptr, hh, 1024, 1024, 256, 0);

    // ybuf = hh @ w2 + b2
    hgemm_k<false, 0><<<dim3(2, 170), 256, 0, stream>>>(
        (const void*)hh, nullptr, w2T, b2, ybuf, nullptr, 256, 256, 1024, 0);

    // out = LN(ybuf + xbuf)
    ln_kernel<false><<<NTOK / 4, 256, 0, stream>>>(ybuf, xbuf, g2, be2, (float*)d_out, nullptr);
}

// Round 5
// 278.246 us; speedup vs baseline: 2.5273x; 1.0242x over previous
//
#include <hip/hip_runtime.h>
#include <hip/hip_fp16.h>
#include <math.h>

// Problem constants (fixed by the reference)
#define LEN   5440          // 64*64 + 32*32 + 16*16 + 8*8
#define NTOK  21760         // B(4) * LEN
#define DFF   1024
#define LEPS  1e-5f

typedef __attribute__((ext_vector_type(8))) _Float16 f16x8;
typedef __attribute__((ext_vector_type(4))) float f32x4;

__device__ __forceinline__ float4 f4_add(float4 a, float4 b) {
    return make_float4(a.x + b.x, a.y + b.y, a.z + b.z, a.w + b.w);
}

__device__ __forceinline__ __half2 u2h2(unsigned u) {
    union { unsigned u; __half2 h; } c; c.u = u; return c.h;
}

// Bijective XCD-chunk swizzle (m204): dispatch-linear id -> tile id such that
// each XCD (= lin%8 round-robin) owns a contiguous tile chunk.
__device__ __forceinline__ int swz8(int lin, int nwg) {
    const int q = nwg >> 3, r = nwg & 7;
    const int x = lin & 7, j = lin >> 3;
    return (x < r ? x * (q + 1) : r * (q + 1) + (x - r) * q) + j;
}

// ---------------- pack: weights -> fp16, transposed to [N][K] ----------------
__global__ __launch_bounds__(256) void pack_k(const float* __restrict__ w_off,
                                              const float* __restrict__ w_attn,
                                              const float* __restrict__ w_val,
                                              const float* __restrict__ b_off,
                                              const float* __restrict__ b_attn,
                                              const float* __restrict__ b_val,
                                              const float* __restrict__ w_out,
                                              const float* __restrict__ w1,
                                              const float* __restrict__ w2,
                                              __half* __restrict__ WcatT,
                                              __half* __restrict__ woutT,
                                              __half* __restrict__ w1T,
                                              __half* __restrict__ w2T,
                                              float* __restrict__ bcat) {
    const int i = blockIdx.x * 256 + threadIdx.x;
    if (i < 163840) {                      // WcatT [c<640][k<256]
        const int c = i >> 8, k = i & 255;
        float v;
        if (c < 256)      v = w_off[k * 256 + c];
        else if (c < 384) v = w_attn[k * 128 + (c - 256)];
        else              v = w_val[k * 256 + (c - 384)];
        WcatT[i] = __float2half(v);
    } else if (i < 229376) {               // woutT [c<256][k<256]
        const int j = i - 163840, c = j >> 8, k = j & 255;
        woutT[j] = __float2half(w_out[k * 256 + c]);
    } else if (i < 491520) {               // w1T [c<1024][k<256]
        const int j = i - 229376, c = j >> 8, k = j & 255;
        w1T[j] = __float2half(w1[k * 1024 + c]);
    } else if (i < 753664) {               // w2T [c<256][k<1024]
        const int j = i - 491520, c = j >> 10, k = j & 1023;
        w2T[j] = __float2half(w2[k * 256 + c]);
    }
    if (i < 640) {
        bcat[i] = (i < 256) ? b_off[i] : (i < 384) ? b_attn[i - 256] : b_val[i - 384];
    }
}

// ---------------- fp16 MFMA GEMM: C[M,N] = A[M,K] @ Bt[N,K]^T + bias ----------------
// 128x128 tile, BK=32, 4 waves, each wave 64x64 via 4x4 frags of 16x16x32 MFMA.
// Register-prefetch pipeline; AF32: A is f32 (+A2f added when bx*128 < colSwitch).
// OMODE: 0 = f32 out; 2 = relu + f16 out; 3 = split f32 / f16-at-(col-colSwitch).
template <bool AF32, int OMODE>
__global__ __launch_bounds__(256) void hgemm_k(const void* __restrict__ Ap,
                                               const float* __restrict__ A2f,
                                               const __half* __restrict__ Bt,
                                               const float* __restrict__ bias,
                                               float* __restrict__ Cf,
                                               __half* __restrict__ Ch,
                                               int NnF, int NnH, int K, int colSwitch) {
    __shared__ __half As[128][40];   // padded stride 40 halfs = 80 B
    __shared__ __half Bs[128][40];
    const int nbx = gridDim.x;
    const int nwg = nbx * gridDim.y;
    const int tile = swz8(blockIdx.y * nbx + blockIdx.x, nwg);
    const int bx = tile % nbx, by = tile / nbx;   // bx fastest: same-A tiles adjacent

    const int tid = threadIdx.x;
    const int lane = tid & 63;
    const int wave = tid >> 6;
    const int wr = (wave >> 1) * 64;
    const int wc = (wave & 1) * 64;
    const bool useA2 = AF32 && (bx * 128 < colSwitch);

    // staging: thread t owns row t>>1, 16 contiguous elements at k-offset (t&1)*16
    const int srow = tid >> 1;
    const int sk = (tid & 1) * 16;

    const __half* Brow   = Bt + (size_t)(bx * 128 + srow) * K + sk;
    const float*  Afrow  = AF32 ? ((const float*)Ap + (size_t)(by * 128 + srow) * K + sk) : nullptr;
    const float*  Pfrow  = useA2 ? (A2f + (size_t)(by * 128 + srow) * K + sk) : nullptr;
    const __half* Ahrow  = AF32 ? nullptr : ((const __half*)Ap + (size_t)(by * 128 + srow) * K + sk);

    f32x4 acc[4][4];
#pragma unroll
    for (int m = 0; m < 4; ++m)
#pragma unroll
        for (int n = 0; n < 4; ++n) acc[m][n] = (f32x4){0.f, 0.f, 0.f, 0.f};

    const int fr = lane & 15;
    const int fk = (lane >> 4) * 8;

    uint4 a0, a1, b0, b1;
    float4 ra0, ra1, ra2, ra3, rp0, rp1, rp2, rp3;

    // prologue: issue loads for k0 = 0
    if (AF32) {
        ra0 = *(const float4*)(Afrow + 0);
        ra1 = *(const float4*)(Afrow + 4);
        ra2 = *(const float4*)(Afrow + 8);
        ra3 = *(const float4*)(Afrow + 12);
        if (useA2) {
            rp0 = *(const float4*)(Pfrow + 0);
            rp1 = *(const float4*)(Pfrow + 4);
            rp2 = *(const float4*)(Pfrow + 8);
            rp3 = *(const float4*)(Pfrow + 12);
        }
    } else {
        a0 = *(const uint4*)(Ahrow + 0);
        a1 = *(const uint4*)(Ahrow + 8);
    }
    b0 = *(const uint4*)(Brow + 0);
    b1 = *(const uint4*)(Brow + 8);

    for (int k0 = 0; k0 < K; k0 += 32) {
        __syncthreads();   // all lanes finished reading LDS from previous step
        if (AF32) {
            float4 f0 = ra0, f1 = ra1, f2 = ra2, f3 = ra3;
            if (useA2) {
                f0 = f4_add(f0, rp0);
                f1 = f4_add(f1, rp1);
                f2 = f4_add(f2, rp2);
                f3 = f4_add(f3, rp3);
            }
            union { __half2 h[8]; uint4 u[2]; } cv;
            cv.h[0] = __floats2half2_rn(f0.x, f0.y);
            cv.h[1] = __floats2half2_rn(f0.z, f0.w);
            cv.h[2] = __floats2half2_rn(f1.x, f1.y);
            cv.h[3] = __floats2half2_rn(f1.z, f1.w);
            cv.h[4] = __floats2half2_rn(f2.x, f2.y);
            cv.h[5] = __floats2half2_rn(f2.z, f2.w);
            cv.h[6] = __floats2half2_rn(f3.x, f3.y);
            cv.h[7] = __floats2half2_rn(f3.z, f3.w);
            a0 = cv.u[0];
            a1 = cv.u[1];
        }
        *(uint4*)&As[srow][sk]     = a0;
        *(uint4*)&As[srow][sk + 8] = a1;
        *(uint4*)&Bs[srow][sk]     = b0;
        *(uint4*)&Bs[srow][sk + 8] = b1;
        __syncthreads();

        const int kn = k0 + 32;
        if (kn < K) {      // uniform branch: prefetch next step into regs
            if (AF32) {
                ra0 = *(const float4*)(Afrow + kn + 0);
                ra1 = *(const float4*)(Afrow + kn + 4);
                ra2 = *(const float4*)(Afrow + kn + 8);
                ra3 = *(const float4*)(Afrow + kn + 12);
                if (useA2) {
                    rp0 = *(const float4*)(Pfrow + kn + 0);
                    rp1 = *(const float4*)(Pfrow + kn + 4);
                    rp2 = *(const float4*)(Pfrow + kn + 8);
                    rp3 = *(const float4*)(Pfrow + kn + 12);
                }
            } else {
                a0 = *(const uint4*)(Ahrow + kn + 0);
                a1 = *(const uint4*)(Ahrow + kn + 8);
            }
            b0 = *(const uint4*)(Brow + kn + 0);
            b1 = *(const uint4*)(Brow + kn + 8);
        }

        f16x8 af[4], bf[4];
#pragma unroll
        for (int m = 0; m < 4; ++m) af[m] = *(const f16x8*)&As[wr + m * 16 + fr][fk];
#pragma unroll
        for (int n = 0; n < 4; ++n) bf[n] = *(const f16x8*)&Bs[wc + n * 16 + fr][fk];
#pragma unroll
        for (int m = 0; m < 4; ++m)
#pragma unroll
            for (int n = 0; n < 4; ++n)
                acc[m][n] = __builtin_amdgcn_mfma_f32_16x16x32_f16(af[m], bf[n], acc[m][n], 0, 0, 0);
    }

    // C/D layout (m89): col = lane&15, row = (lane>>4)*4 + reg
    const int rowb = by * 128 + wr + (lane >> 4) * 4;
    const int colb = bx * 128 + wc + fr;
    float bn[4];
#pragma unroll
    for (int n = 0; n < 4; ++n) bn[n] = bias[colb + n * 16];
    const bool vhalf = (OMODE == 2) || (OMODE == 3 && bx * 128 >= colSwitch);
    const int colh = (OMODE == 3) ? (colb - colSwitch) : colb;
#pragma unroll
    for (int m = 0; m < 4; ++m) {
#pragma unroll
        for (int r = 0; r < 4; ++r) {
            const int row = rowb + m * 16 + r;
#pragma unroll
            for (int n = 0; n < 4; ++n) {
                float v = acc[m][n][r] + bn[n];
                if (OMODE == 2) v = fmaxf(v, 0.f);
                if (vhalf) Ch[(size_t)row * NnH + colh + n * 16] = __float2half(v);
                else       Cf[(size_t)row * NnF + colb + n * 16] = v;
            }
        }
    }
}

// ---------------- MSDA: two-phase (descriptor prep in LDS, then fp16 gather) ----
// C1a row layout per token n: [0,256) offsets, [256,384) attn logits (f32, stride 384)
// Vh: [N,256] fp16 value. Block = 256 threads = 2 tokens * 8 heads * 16 lanes.
// Phase 2: lane si -> corner-block (si>>2) x channel-octet (si&3). All math in
// packed fp16 (v_pk_fma_f16): weights pre-packed as half2(w,w) in phase 1; each
// corner costs 1 dwordx4 load + 4 pk_fma. Partial sums promoted to f32 before
// the cross-lane reduce (fp16 run is 16 convex adds -> ~3e-3 worst-case).
__global__ __launch_bounds__(256) void msda_kernel(const float* __restrict__ C1a,
                                                   const __half* __restrict__ Vh,
                                                   const float* __restrict__ refp,
                                                   __half* __restrict__ out) {
    __shared__ int      sOff[16][17][4];   // byte offsets into Vh (pos*512 + h*64)
    __shared__ unsigned sWh[16][17][4];    // packed half2(w, w)
    const int tid = threadIdx.x;
    const int gi = tid >> 4;           // (token,head) group 0..15
    const int si = tid & 15;
    const int tile = swz8(blockIdx.x, gridDim.x);   // NTOK/2 divisible by 8
    const int n = tile * 2 + (gi >> 3);
    const int h = gi & 7;
    const int b = n / LEN;

    // ---- phase 1: one lane per (l,p) sample computes softmax + corner descriptors
    {
        const int l = si >> 2, p = si & 3;
        const float lg = C1a[(size_t)n * 384 + 256 + h * 16 + si];
        float mx = lg;
#pragma unroll
        for (int m = 1; m < 16; m <<= 1) mx = fmaxf(mx, __shfl_xor(mx, m, 16));
        const float e = __expf(lg - mx);
        float sum = e;
#pragma unroll
        for (int m = 1; m < 16; m <<= 1) sum += __shfl_xor(sum, m, 16);
        const float aw = e / sum;

        const int Wi[4] = {64, 32, 16, 8};
        const int st[4] = {0, 4096, 5120, 5376};
        const int W = Wi[l];
        const float Wf = (float)W;
        const float rx = refp[((size_t)n * 4 + l) * 2 + 0];
        const float ry = refp[((size_t)n * 4 + l) * 2 + 1];
        const float2 oxy = *(const float2*)&C1a[(size_t)n * 384 + (((h * 4 + l) * 4 + p) * 2)];
        // match reference op order: loc = ref + off/W ; px = loc*W - 0.5
        const float lx = rx + oxy.x / Wf;
        const float ly = ry + oxy.y / Wf;
        const float px = lx * Wf - 0.5f;
        const float py = ly * Wf - 0.5f;
        const float x0f = floorf(px), y0f = floorf(py);
        const float wx1 = px - x0f, wy1 = py - y0f;
        const int x0 = (int)x0f, y0 = (int)y0f;
#pragma unroll
        for (int c = 0; c < 4; ++c) {
            const int dx = c & 1, dy = c >> 1;
            const int ix = x0 + dx, iy = y0 + dy;
            const float wgt = (dx ? wx1 : 1.f - wx1) * (dy ? wy1 : 1.f - wy1);
            const bool valid = (ix >= 0) && (ix < W) && (iy >= 0) && (iy < W);
            const int ixc = min(max(ix, 0), W - 1);
            const int iyc = min(max(iy, 0), W - 1);
            const int pos = st[l] + iyc * W + ixc;
            sOff[gi][si][c] = ((b * LEN + pos) << 9) + (h << 6);   // BYTE offset
            const float wa = valid ? (aw * wgt) : 0.f;
            const unsigned wu = (unsigned)__half_as_ushort(__float2half_rn(wa));
            sWh[gi][si][c] = wu | (wu << 16);
        }
    }
    __syncthreads();

    // ---- phase 2: 16 corners x 8 channels per lane, all packed fp16
    const int cbyte = (si & 3) * 16;    // channel-octet byte offset within h-slice
    const int sb = (si >> 2) * 4;       // first sample of this lane's block
    __half2 acc0 = u2h2(0), acc1 = u2h2(0), acc2 = u2h2(0), acc3 = u2h2(0);
    const char* Vb = (const char*)Vh;
#pragma unroll
    for (int t = 0; t < 4; ++t) {
        const int s = sb + t;
        const int4  off = *(const int4*)&sOff[gi][s][0];
        const uint4 wq  = *(const uint4*)&sWh[gi][s][0];
        union { uint4 u; __half2 h2[4]; } v0, v1, v2, v3;
        v0.u = *(const uint4*)(Vb + off.x + cbyte);
        v1.u = *(const uint4*)(Vb + off.y + cbyte);
        v2.u = *(const uint4*)(Vb + off.z + cbyte);
        v3.u = *(const uint4*)(Vb + off.w + cbyte);
        const __half2 w0 = u2h2(wq.x), w1 = u2h2(wq.y), w2 = u2h2(wq.z), w3 = u2h2(wq.w);
        acc0 = __hfma2(v0.h2[0], w0, acc0);
        acc1 = __hfma2(v0.h2[1], w0, acc1);
        acc2 = __hfma2(v0.h2[2], w0, acc2);
        acc3 = __hfma2(v0.h2[3], w0, acc3);
        acc0 = __hfma2(v1.h2[0], w1, acc0);
        acc1 = __hfma2(v1.h2[1], w1, acc1);
        acc2 = __hfma2(v1.h2[2], w1, acc2);
        acc3 = __hfma2(v1.h2[3], w1, acc3);
        acc0 = __hfma2(v2.h2[0], w2, acc0);
        acc1 = __hfma2(v2.h2[1], w2, acc1);
        acc2 = __hfma2(v2.h2[2], w2, acc2);
        acc3 = __hfma2(v2.h2[3], w2, acc3);
        acc0 = __hfma2(v3.h2[0], w3, acc0);
        acc1 = __hfma2(v3.h2[1], w3, acc1);
        acc2 = __hfma2(v3.h2[2], w3, acc2);
        acc3 = __hfma2(v3.h2[3], w3, acc3);
    }
    // promote to f32, then reduce across the 4 corner-blocks (si^4, si^8)
    float f0 = __low2float(acc0), f1 = __high2float(acc0);
    float f2 = __low2float(acc1), f3 = __high2float(acc1);
    float f4 = __low2float(acc2), f5 = __high2float(acc2);
    float f6 = __low2float(acc3), f7 = __high2float(acc3);
#pragma unroll
    for (int m = 4; m <= 8; m <<= 1) {
        f0 += __shfl_xor(f0, m, 64);
        f1 += __shfl_xor(f1, m, 64);
        f2 += __shfl_xor(f2, m, 64);
        f3 += __shfl_xor(f3, m, 64);
        f4 += __shfl_xor(f4, m, 64);
        f5 += __shfl_xor(f5, m, 64);
        f6 += __shfl_xor(f6, m, 64);
        f7 += __shfl_xor(f7, m, 64);
    }
    if (si < 4) {
        union { __half2 h2[4]; uint4 u; } O;
        O.h2[0] = __floats2half2_rn(f0, f1);
        O.h2[1] = __floats2half2_rn(f2, f3);
        O.h2[2] = __floats2half2_rn(f4, f5);
        O.h2[3] = __floats2half2_rn(f6, f7);
        *(uint4*)&out[(size_t)n * 256 + h * 32 + si * 8] = O.u;
    }
}

// ---------------- LayerNorm (wave per token): O = LN(Y + R) * g + b ----------------
template <bool WH>
__global__ __launch_bounds__(256) void ln_kernel(const float* __restrict__ Y,
                                                 const float* __restrict__ R,
                                                 const float* __restrict__ gm,
                                                 const float* __restrict__ bt,
                                                 float* __restrict__ O,
                                                 __half* __restrict__ OH) {
    const int wave = threadIdx.x >> 6, lane = threadIdx.x & 63;
    const int n = blockIdx.x * 4 + wave;
    const size_t base = (size_t)n * 256 + lane * 4;
    float4 y = *(const float4*)&Y[base];
    float4 r = *(const float4*)&R[base];
    float4 v = f4_add(y, r);
    float s = v.x + v.y + v.z + v.w;
#pragma unroll
    for (int m = 1; m < 64; m <<= 1) s += __shfl_xor(s, m, 64);
    const float mean = s * (1.f / 256.f);
    const float dx = v.x - mean, dy = v.y - mean, dz = v.z - mean, dw = v.w - mean;
    float ss = dx * dx + dy * dy + dz * dz + dw * dw;
#pragma unroll
    for (int m = 1; m < 64; m <<= 1) ss += __shfl_xor(ss, m, 64);
    const float rstd = rsqrtf(ss * (1.f / 256.f) + LEPS);
    const float4 g4 = *(const float4*)&gm[lane * 4];
    const float4 b4 = *(const float4*)&bt[lane * 4];
    float4 o;
    o.x = dx * rstd * g4.x + b4.x;
    o.y = dy * rstd * g4.y + b4.y;
    o.z = dz * rstd * g4.z + b4.z;
    o.w = dw * rstd * g4.w + b4.w;
    *(float4*)&O[base] = o;
    if (WH) {
        union { __half2 h[2]; uint2 u; } Hh;
        Hh.h[0] = __floats2half2_rn(o.x, o.y);
        Hh.h[1] = __floats2half2_rn(o.z, o.w);
        *(uint2*)&OH[base] = Hh.u;
    }
}

// ---------------- launch ----------------
extern "C" void kernel_launch(void* const* d_in, const int* in_sizes, int n_in,
                              void* d_out, int out_size, void* d_ws, size_t ws_size,
                              hipStream_t stream) {
    const float* src   = (const float*)d_in[0];
    const float* pos   = (const float*)d_in[1];
    const float* refp  = (const float*)d_in[2];
    const float* w_off  = (const float*)d_in[6];
    const float* b_off  = (const float*)d_in[7];
    const float* w_attn = (const float*)d_in[8];
    const float* b_attn = (const float*)d_in[9];
    const float* w_val  = (const float*)d_in[10];
    const float* b_val  = (const float*)d_in[11];
    const float* w_out  = (const float*)d_in[12];
    const float* b_out  = (const float*)d_in[13];
    const float* g1     = (const float*)d_in[14];
    const float* be1    = (const float*)d_in[15];
    const float* w1     = (const float*)d_in[16];
    const float* b1     = (const float*)d_in[17];
    const float* w2     = (const float*)d_in[18];
    const float* b2     = (const float*)d_in[19];
    const float* g2     = (const float*)d_in[20];
    const float* be2    = (const float*)d_in[21];

    float* ws = (float*)d_ws;
    // workspace layout (float offsets); total ~33.8M floats ~= 135 MB
    float*  C1a   = ws + 0;                       // [N,384] f32 off|logits; ybuf alias
    __half* Vh    = (__half*)(ws + 8355840);      // [N,256] f16 value
    __half* msdah = (__half*)(ws + 11141120);     // [N,256] f16
    float*  xbuf  = ws + 13926400;                // [N,256] f32
    __half* xh    = (__half*)(ws + 19496960);     // [N,256] f16
    __half* hh    = (__half*)(ws + 22282240);     // [N,1024] f16
    __half* WcatT = (__half*)(ws + 33423360);     // [640][256] f16
    __half* woutT = (__half*)(ws + 33505280);     // [256][256] f16
    __half* w1T   = (__half*)(ws + 33538048);     // [1024][256] f16
    __half* w2T   = (__half*)(ws + 33669120);     // [256][1024] f16
    float*  bcat  = ws + 33800192;                // [640] f32
    float*  ybuf  = C1a;                          // C1a dead after msda

    pack_k<<<2944, 256, 0, stream>>>(w_off, w_attn, w_val, b_off, b_attn, b_val,
                                     w_out, w1, w2, WcatT, woutT, w1T, w2T, bcat);

    // GEMM1: [N,640] = (half(src+pos) | half(src)) @ Wcat + bcat
    //   cols [0,384) -> C1a f32 ; cols [384,640) -> Vh f16
    hgemm_k<true, 3><<<dim3(5, 170), 256, 0, stream>>>(
        (const void*)src, pos, WcatT, bcat, C1a, Vh, 384, 256, 256, 384);

    msda_kernel<<<NTOK / 2, 256, 0, stream>>>(C1a, Vh, refp, msdah);

    // ybuf = msda @ w_out + b_out
    hgemm_k<false, 0><<<dim3(2, 170), 256, 0, stream>>>(
        (const void*)msdah, nullptr, woutT, b_out, ybuf, nullptr, 256, 256, 256, 0);

    // x = LN(ybuf + src) -> xbuf (f32) and xh (f16)
    ln_kernel<true><<<NTOK / 4, 256, 0, stream>>>(ybuf, src, g1, be1, xbuf, xh);

    // hh = relu(x @ w1 + b1)  (f16)
    hgemm_k<false, 2><<<dim3(8, 170), 256, 0, stream>>>(
        (const void*)xh, nullptr, w1T, b1, nullptr, hh, 1024, 1024, 256, 0);

    // ybuf = hh @ w2 + b2
    hgemm_k<false, 0><<<dim3(2, 170), 256, 0, stream>>>(
        (const void*)hh, nullptr, w2T, b2, ybuf, nullptr, 256, 256, 1024, 0);

    // out = LN(ybuf + xbuf)
    ln_kernel<false><<<NTOK / 4, 256, 0, stream>>>(ybuf, xbuf, g2, be2, (float*)d_out, nullptr);
}